// Round 3
// baseline (256.305 us; speedup 1.0000x reference)
//
#include <hip/hip_runtime.h>
#include <hip/hip_bf16.h>
#include <math.h>

#define Bb 4
#define Nn 4096
#define Hh 64
#define T1c 3072

typedef unsigned short ushort_t;
typedef __bf16 bf16x8 __attribute__((ext_vector_type(8)));
typedef float floatx4 __attribute__((ext_vector_type(4)));
typedef unsigned short ushort4v __attribute__((ext_vector_type(4)));

// Internal scratch (always bf16), fully rewritten by qkvt every call.
__device__ ushort_t g_qw[(size_t)Bb * Nn * Hh];
__device__ ushort_t g_kw[(size_t)Bb * Nn * Hh];
__device__ ushort_t g_vt[(size_t)Bb * Nn * Hh];   // [B][H][N] transposed V
__device__ ushort_t g_dt[(size_t)Bb * Nn * Hh];

__device__ __forceinline__ float bf2f(unsigned short u) {
    union { unsigned int i; float f; } c;
    c.i = ((unsigned int)u) << 16;
    return c.f;
}
__device__ __forceinline__ unsigned short f2bf(float f) {
    union { float f; unsigned int i; } c;
    c.f = f;
    unsigned int x = c.i;
    unsigned int r = (x + 0x7fffu + ((x >> 16) & 1u)) >> 16;  // RNE
    return (unsigned short)r;
}

// dtype-adaptive loaders: eidx is an ELEMENT index (in_sizes are element counts)
__device__ __forceinline__ bf16x8 ld8(const void* p, size_t eidx, bool f32) {
    if (f32) {
        const float* fp = (const float*)p + eidx;
        float4 x0 = *(const float4*)fp;
        float4 x1 = *(const float4*)(fp + 4);
        bf16x8 r;
        r[0] = (__bf16)x0.x; r[1] = (__bf16)x0.y; r[2] = (__bf16)x0.z; r[3] = (__bf16)x0.w;
        r[4] = (__bf16)x1.x; r[5] = (__bf16)x1.y; r[6] = (__bf16)x1.z; r[7] = (__bf16)x1.w;
        return r;
    }
    return *(const bf16x8*)((const ushort_t*)p + eidx);
}
__device__ __forceinline__ float ldS(const void* p, size_t eidx, bool f32) {
    return f32 ? ((const float*)p)[eidx] : bf2f(((const ushort_t*)p)[eidx]);
}
__device__ __forceinline__ void stOut(void* p, size_t eidx, float v, bool f32) {
    if (f32) ((float*)p)[eidx] = v;
    else ((ushort_t*)p)[eidx] = f2bf(v);
}

__device__ __forceinline__ floatx4 mfma16(bf16x8 a, bf16x8 b, floatx4 c) {
    return __builtin_amdgcn_mfma_f32_16x16x32_bf16(a, b, c, 0, 0, 0);
}

// ---------------------------------------------------------------------------
// Phase A: q = h@Wq^T, k = h@Wk^T, vT = (h@Wv^T)^T, dt = tanh((h@Wt^T+bt)/2)
// grid: B*(N/64) blocks x 256 threads; wave w handles 16 rows.
// ---------------------------------------------------------------------------
__global__ __launch_bounds__(256) void qkvt_kernel(
    const void* __restrict__ hid, const void* __restrict__ adj,
    const void* __restrict__ Wq, const void* __restrict__ Wk,
    const void* __restrict__ Wv,
    const void* __restrict__ Wti, const void* __restrict__ bti,
    const void* __restrict__ Wto, const void* __restrict__ bto)
{
    // dtype probe: adjacency[0][0] == 1.0 guaranteed. fp32 -> first u32 is
    // 0x3F800000; bf16 -> low halfword is 0x3F80 (never 0x0000).
    const bool F32 = (*(const unsigned*)adj) == 0x3F800000u;

    const int bi = blockIdx.x;
    const int b = bi >> 6;
    const int n0 = (bi & 63) << 6;
    const int t = threadIdx.x;
    const int wv = t >> 6, lane = t & 63, l16 = lane & 15, quad = lane >> 4;
    const int nw = n0 + wv * 16;
    const bool inter = (n0 < T1c);
    const void* Wt = inter ? Wti : Wto;
    const void* bt = inter ? bti : bto;

    // A fragments: h[n][k], lane row = l16, k = quad*8 + j
    const size_t hbase = ((size_t)(b * Nn + nw + l16)) * Hh + quad * 8;
    bf16x8 a0 = ld8(hid, hbase, F32);
    bf16x8 a1 = ld8(hid, hbase + 32, F32);
    floatx4 z = {0.f, 0.f, 0.f, 0.f};

    floatx4 cq[4], ck[4], cv[4], ct[4];
#pragma unroll
    for (int ti = 0; ti < 4; ++ti) {
        const size_t wrow = (size_t)(ti * 16 + l16) * 64 + quad * 8;
        bf16x8 w0, w1;
        w0 = ld8(Wq, wrow, F32); w1 = ld8(Wq, wrow + 32, F32);
        cq[ti] = mfma16(a1, w1, mfma16(a0, w0, z));
        w0 = ld8(Wk, wrow, F32); w1 = ld8(Wk, wrow + 32, F32);
        ck[ti] = mfma16(a1, w1, mfma16(a0, w0, z));
        w0 = ld8(Wv, wrow, F32); w1 = ld8(Wv, wrow + 32, F32);
        cv[ti] = mfma16(a1, w1, mfma16(a0, w0, z));
        w0 = ld8(Wt, wrow, F32); w1 = ld8(Wt, wrow + 32, F32);
        ct[ti] = mfma16(a1, w1, mfma16(a0, w0, z));
    }

#pragma unroll
    for (int ti = 0; ti < 4; ++ti) {
        // q, k: row-major stores (C layout: col = ti*16+l16, row = quad*4+r)
#pragma unroll
        for (int r = 0; r < 4; ++r) {
            const size_t idx = ((size_t)(b * Nn + nw + quad * 4 + r)) * 64 + ti * 16 + l16;
            g_qw[idx] = f2bf(cq[ti][r]);
            g_kw[idx] = f2bf(ck[ti][r]);
        }
        // v transposed: vT[b][d][n], 4 consecutive n -> one 8B store
        {
            uint2 pk;
            pk.x = (unsigned)f2bf(cv[ti][0]) | ((unsigned)f2bf(cv[ti][1]) << 16);
            pk.y = (unsigned)f2bf(cv[ti][2]) | ((unsigned)f2bf(cv[ti][3]) << 16);
            *(uint2*)&g_vt[((size_t)(b * 64 + ti * 16 + l16)) * Nn + nw + quad * 4] = pk;
        }
        // dt = tanh(0.5*(h@Wt^T + bt))
        {
            const float btv = ldS(bt, ti * 16 + l16, F32);
#pragma unroll
            for (int r = 0; r < 4; ++r) {
                const size_t idx = ((size_t)(b * Nn + nw + quad * 4 + r)) * 64 + ti * 16 + l16;
                g_dt[idx] = f2bf(tanhf(0.5f * (ct[ti][r] + btv)));
            }
        }
    }
}

// ---------------------------------------------------------------------------
// Phase B: fused masked attention + L2-norm + PV + epilogue.
// grid: B*(N/64) = 256 blocks x 256 threads (4 waves x 16 rows each).
// ---------------------------------------------------------------------------
__global__ __launch_bounds__(256) void attn_kernel(
    const void* __restrict__ hid, const void* __restrict__ adj,
    const void* __restrict__ Wui, const void* __restrict__ bui,
    const void* __restrict__ Wuo, const void* __restrict__ buo,
    const void* __restrict__ stepp, void* __restrict__ outp)
{
    const bool F32 = (*(const unsigned*)adj) == 0x3F800000u;

    // +8 element row padding (rows of 72) to break power-of-2 LDS strides
    __shared__ ushort_t adjT[64 * 72];  // [m][n] tile of adjacency
    __shared__ ushort_t kT[64 * 72];    // [m][h]
    __shared__ ushort_t vTl[64 * 72];   // [d][m]
    __shared__ ushort_t sS[64 * 72];    // masked S [n][m], per-wave 16-row slabs

    const int bi = blockIdx.x;
    const int b = bi >> 6;
    const int n0 = (bi & 63) << 6;
    const int t = threadIdx.x;
    const int wv = t >> 6, lane = t & 63, l16 = lane & 15, quad = lane >> 4;
    const int nw = n0 + wv * 16;
    const int nnb = wv * 16 + quad * 4;  // this lane's row group within the block

    // Q A-fragments (row = l16, k = quad*8+j), held for the whole kernel
    const size_t qbase = ((size_t)(b * Nn + nw + l16)) * 64 + quad * 8;
    bf16x8 a0 = *(const bf16x8*)&g_qw[qbase];
    bf16x8 a1 = *(const bf16x8*)&g_qw[qbase + 32];

    floatx4 z = {0.f, 0.f, 0.f, 0.f};
    floatx4 acc[4];
    float ssq[4];
#pragma unroll
    for (int i = 0; i < 4; ++i) { acc[i] = z; ssq[i] = 0.f; }

    int srow[2], scol[2];
#pragma unroll
    for (int i = 0; i < 2; ++i) { const int c = t + 256 * i; srow[i] = c >> 3; scol[i] = (c & 7) * 8; }

    for (int it = 0; it < 64; ++it) {
        const int m0 = it * 64;

        // stage this m-tile
#pragma unroll
        for (int i = 0; i < 2; ++i) {
            *(bf16x8*)&adjT[srow[i] * 72 + scol[i]] =
                ld8(adj, (size_t)(m0 + srow[i]) * Nn + n0 + scol[i], F32);
            *(bf16x8*)&kT[srow[i] * 72 + scol[i]] =
                *(const bf16x8*)&g_kw[((size_t)(b * Nn + m0 + srow[i])) * 64 + scol[i]];
            *(bf16x8*)&vTl[srow[i] * 72 + scol[i]] =
                *(const bf16x8*)&g_vt[((size_t)(b * 64 + srow[i])) * Nn + m0 + scol[i]];
        }
        __syncthreads();

        // S = Q K^T (C layout: col = m = l16, row = n = quad*4+r), mask, sumsq
#pragma unroll
        for (int tm = 0; tm < 4; ++tm) {
            const ushort_t* kb = &kT[(tm * 16 + l16) * 72];
            bf16x8 k0 = *(const bf16x8*)(kb + quad * 8);
            bf16x8 k1 = *(const bf16x8*)(kb + 32 + quad * 8);
            floatx4 sv = mfma16(a1, k1, mfma16(a0, k0, z));
            // mask[n,m] = adjacency[m][n]: 4 consecutive n per lane -> b64 read
            ushort4v mv = *(const ushort4v*)&adjT[(tm * 16 + l16) * 72 + nnb];
#pragma unroll
            for (int r = 0; r < 4; ++r) {
                const float sm = sv[r] * bf2f(mv[r]);
                ssq[r] += sm * sm;
                sS[(nnb + r) * 72 + tm * 16 + l16] = f2bf(sm);
            }
        }
        __syncthreads();

        // read S back in A layout, PV
        bf16x8 sa0 = *(const bf16x8*)&sS[(wv * 16 + l16) * 72 + quad * 8];
        bf16x8 sa1 = *(const bf16x8*)&sS[(wv * 16 + l16) * 72 + 32 + quad * 8];
#pragma unroll
        for (int td = 0; td < 4; ++td) {
            const ushort_t* vb = &vTl[(td * 16 + l16) * 72];
            bf16x8 v0 = *(const bf16x8*)(vb + quad * 8);
            bf16x8 v1 = *(const bf16x8*)(vb + 32 + quad * 8);
            acc[td] = mfma16(sa0, v0, acc[td]);
            acc[td] = mfma16(sa1, v1, acc[td]);
        }
        __syncthreads();
    }

    // row L2 norms: reduce ssq across the 16 lanes (l16) of each row group
#pragma unroll
    for (int r = 0; r < 4; ++r) {
        float v = ssq[r];
        v += __shfl_xor(v, 1, 64);
        v += __shfl_xor(v, 2, 64);
        v += __shfl_xor(v, 4, 64);
        v += __shfl_xor(v, 8, 64);
        ssq[r] = v;
    }
    float inv[4];
#pragma unroll
    for (int r = 0; r < 4; ++r) inv[r] = (ssq[r] > 0.f) ? (1.0f / sqrtf(ssq[r])) : 0.f;

    // epilogue: u = (acc/norm) @ Wu^T + bu ; out = h + step*dt*u
#pragma unroll
    for (int td = 0; td < 4; ++td)
#pragma unroll
        for (int r = 0; r < 4; ++r)
            sS[(nnb + r) * 72 + td * 16 + l16] = f2bf(acc[td][r] * inv[r]);
    __syncthreads();

    bf16x8 ua0 = *(const bf16x8*)&sS[(wv * 16 + l16) * 72 + quad * 8];
    bf16x8 ua1 = *(const bf16x8*)&sS[(wv * 16 + l16) * 72 + 32 + quad * 8];

    const bool inter = (n0 < T1c);
    const void* Wu = inter ? Wui : Wuo;
    const void* bu = inter ? bui : buo;

    const float step = ldS(stepp, 0, F32);

#pragma unroll
    for (int ti = 0; ti < 4; ++ti) {
        const size_t wrow = (size_t)(ti * 16 + l16) * 64 + quad * 8;
        bf16x8 w0 = ld8(Wu, wrow, F32);
        bf16x8 w1 = ld8(Wu, wrow + 32, F32);
        floatx4 u = mfma16(ua1, w1, mfma16(ua0, w0, z));
        const float buv = ldS(bu, ti * 16 + l16, F32);
#pragma unroll
        for (int r = 0; r < 4; ++r) {
            const size_t idx = ((size_t)(b * Nn + nw + quad * 4 + r)) * 64 + ti * 16 + l16;
            const float hv = ldS(hid, idx, F32);
            const float dtv = bf2f(g_dt[idx]);
            stOut(outp, idx, hv + step * dtv * (u[r] + buv), F32);
        }
    }
}

extern "C" void kernel_launch(void* const* d_in, const int* in_sizes, int n_in,
                              void* d_out, int out_size, void* d_ws, size_t ws_size,
                              hipStream_t stream)
{
    const void* hid = d_in[0];
    // d_in[1] input_states: unused by the reference
    const void* adj = d_in[2];
    const void* Wq  = d_in[3];
    const void* Wk  = d_in[4];
    const void* Wv  = d_in[5];
    const void* Wui = d_in[6];
    const void* bui = d_in[7];
    const void* Wti = d_in[8];
    const void* bti = d_in[9];
    const void* Wuo = d_in[10];
    const void* buo = d_in[11];
    const void* Wto = d_in[12];
    const void* bto = d_in[13];
    const void* stepp = d_in[14];

    qkvt_kernel<<<dim3(Bb * (Nn / 64)), dim3(256), 0, stream>>>(
        hid, adj, Wq, Wk, Wv, Wti, bti, Wto, bto);
    attn_kernel<<<dim3(Bb * (Nn / 64)), dim3(256), 0, stream>>>(
        hid, adj, Wui, bui, Wuo, buo, stepp, (void*)d_out);
}

// Round 4
// 200.478 us; speedup vs baseline: 1.2785x; 1.2785x over previous
//
#include <hip/hip_runtime.h>
#include <hip/hip_bf16.h>
#include <math.h>

#define Bb 4
#define Nn 4096
#define Hh 64
#define T1c 3072
#define MC 4           // split-m chunks in attn_part

typedef unsigned short ushort_t;
typedef __bf16 bf16x8 __attribute__((ext_vector_type(8)));
typedef float floatx4 __attribute__((ext_vector_type(4)));
typedef unsigned short ushort4v __attribute__((ext_vector_type(4)));

// Static device scratch, fully rewritten every call (no cross-call state).
__device__ ushort_t g_qw[(size_t)Bb * Nn * Hh];
__device__ ushort_t g_kw[(size_t)Bb * Nn * Hh];
__device__ ushort_t g_vt[(size_t)Bb * Nn * Hh];   // [B][H][N] transposed V
__device__ ushort_t g_dt[(size_t)Bb * Nn * Hh];
__device__ float    g_pac[(size_t)Bb * 64 * MC * 64 * 64]; // partial acc [b][nt][mc][n][d]
__device__ float    g_pss[(size_t)Bb * 64 * MC * 64];      // partial ssq [b][nt][mc][n]

__device__ __forceinline__ float bf2f(unsigned short u) {
    union { unsigned int i; float f; } c;
    c.i = ((unsigned int)u) << 16;
    return c.f;
}
__device__ __forceinline__ unsigned short f2bf(float f) {
    union { float f; unsigned int i; } c;
    c.f = f;
    unsigned int x = c.i;
    unsigned int r = (x + 0x7fffu + ((x >> 16) & 1u)) >> 16;  // RNE
    return (unsigned short)r;
}

// dtype-adaptive loaders (eidx = element index); F32 is the measured reality,
// bf16 path kept as a cheap uniform-branch hedge.
__device__ __forceinline__ bf16x8 ld8(const void* p, size_t eidx, bool f32) {
    if (f32) {
        const float* fp = (const float*)p + eidx;
        float4 x0 = *(const float4*)fp;
        float4 x1 = *(const float4*)(fp + 4);
        bf16x8 r;
        r[0] = (__bf16)x0.x; r[1] = (__bf16)x0.y; r[2] = (__bf16)x0.z; r[3] = (__bf16)x0.w;
        r[4] = (__bf16)x1.x; r[5] = (__bf16)x1.y; r[6] = (__bf16)x1.z; r[7] = (__bf16)x1.w;
        return r;
    }
    return *(const bf16x8*)((const ushort_t*)p + eidx);
}
__device__ __forceinline__ float ldS(const void* p, size_t eidx, bool f32) {
    return f32 ? ((const float*)p)[eidx] : bf2f(((const ushort_t*)p)[eidx]);
}
__device__ __forceinline__ void stOut(void* p, size_t eidx, float v, bool f32) {
    if (f32) ((float*)p)[eidx] = v;
    else ((ushort_t*)p)[eidx] = f2bf(v);
}

__device__ __forceinline__ floatx4 mfma16(bf16x8 a, bf16x8 b, floatx4 c) {
    return __builtin_amdgcn_mfma_f32_16x16x32_bf16(a, b, c, 0, 0, 0);
}

__device__ __forceinline__ float fast_tanh(float x) {
    float e = __expf(-2.0f * fabsf(x));
    float t = (1.0f - e) / (1.0f + e);
    return copysignf(t, x);
}

// ---------------------------------------------------------------------------
// Phase A: grid B*(N/16)=1024 blocks x 256 thr. Block = 16 rows; the 4 waves
// split by output: wv0->q, wv1->k, wv2->vT, wv3->dt. 16 waves/CU.
// ---------------------------------------------------------------------------
__global__ __launch_bounds__(256) void qkvt_kernel(
    const void* __restrict__ hid, const void* __restrict__ adj,
    const void* __restrict__ Wq, const void* __restrict__ Wk,
    const void* __restrict__ Wv,
    const void* __restrict__ Wti, const void* __restrict__ bti,
    const void* __restrict__ Wto, const void* __restrict__ bto)
{
    const bool F32 = (*(const unsigned*)adj) == 0x3F800000u;

    const int bi = blockIdx.x;
    const int b = bi >> 8;
    const int n16 = (bi & 255) << 4;
    const int t = threadIdx.x;
    const int wv = t >> 6, lane = t & 63, l16 = lane & 15, quad = lane >> 4;
    const bool inter = (n16 < T1c);

    const void* W = (wv == 0) ? Wq : (wv == 1) ? Wk : (wv == 2) ? Wv
                    : (inter ? Wti : Wto);
    const void* bt = inter ? bti : bto;

    // A fragments: h rows n16+l16, k = quad*8 + j (+32 for a1)
    const size_t hbase = ((size_t)(b * Nn + n16 + l16)) * Hh + quad * 8;
    bf16x8 a0 = ld8(hid, hbase, F32);
    bf16x8 a1 = ld8(hid, hbase + 32, F32);
    floatx4 z = {0.f, 0.f, 0.f, 0.f};

    floatx4 c[4];
#pragma unroll
    for (int ti = 0; ti < 4; ++ti) {
        const size_t wrow = (size_t)(ti * 16 + l16) * 64 + quad * 8;
        bf16x8 w0 = ld8(W, wrow, F32);
        bf16x8 w1 = ld8(W, wrow + 32, F32);
        c[ti] = mfma16(a1, w1, mfma16(a0, w0, z));
    }

    // C layout: element [n = n16 + quad*4 + r][d = ti*16 + l16]
    if (wv == 0 || wv == 1) {
        ushort_t* dst = (wv == 0) ? g_qw : g_kw;
#pragma unroll
        for (int ti = 0; ti < 4; ++ti)
#pragma unroll
            for (int r = 0; r < 4; ++r)
                dst[((size_t)(b * Nn + n16 + quad * 4 + r)) * 64 + ti * 16 + l16] = f2bf(c[ti][r]);
    } else if (wv == 2) {
#pragma unroll
        for (int ti = 0; ti < 4; ++ti) {
            uint2 pk;
            pk.x = (unsigned)f2bf(c[ti][0]) | ((unsigned)f2bf(c[ti][1]) << 16);
            pk.y = (unsigned)f2bf(c[ti][2]) | ((unsigned)f2bf(c[ti][3]) << 16);
            *(uint2*)&g_vt[((size_t)(b * 64 + ti * 16 + l16)) * Nn + n16 + quad * 4] = pk;
        }
    } else {
#pragma unroll
        for (int ti = 0; ti < 4; ++ti) {
            const float btv = ldS(bt, ti * 16 + l16, F32);
#pragma unroll
            for (int r = 0; r < 4; ++r)
                g_dt[((size_t)(b * Nn + n16 + quad * 4 + r)) * 64 + ti * 16 + l16] =
                    f2bf(fast_tanh(0.5f * (c[ti][r] + btv)));
        }
    }
}

// ---------------------------------------------------------------------------
// Phase B: split-m attention partials. grid B*64*MC = 1024 blocks x 256 thr.
// Block (b, nt, mc) processes m in [mc*1024, mc*1024+1024), writes partial
// acc (64x64 fp32) + partial ssq (64 fp32). 4 blocks/CU -> 16 waves/CU.
// ---------------------------------------------------------------------------
__global__ __launch_bounds__(256) void attn_part_kernel(
    const void* __restrict__ adj)
{
    const bool F32 = (*(const unsigned*)adj) == 0x3F800000u;

    __shared__ ushort_t adjT[64 * 72];  // [m][n]
    __shared__ ushort_t kT[64 * 72];    // [m][h]
    __shared__ ushort_t vTl[64 * 72];   // [d][m]
    __shared__ ushort_t sS[64 * 72];    // masked S [n][m]

    const int bi = blockIdx.x;
    const int b = bi & 3;
    const int mc = (bi >> 2) & 3;
    const int nt = bi >> 4;
    const int n0 = nt << 6;
    const int t = threadIdx.x;
    const int wv = t >> 6, lane = t & 63, l16 = lane & 15, quad = lane >> 4;
    const int nw = n0 + wv * 16;
    const int nnb = wv * 16 + quad * 4;

    const size_t qbase = ((size_t)(b * Nn + nw + l16)) * 64 + quad * 8;
    bf16x8 a0 = *(const bf16x8*)&g_qw[qbase];
    bf16x8 a1 = *(const bf16x8*)&g_qw[qbase + 32];

    floatx4 z = {0.f, 0.f, 0.f, 0.f};
    floatx4 acc[4];
    float ssq[4];
#pragma unroll
    for (int i = 0; i < 4; ++i) { acc[i] = z; ssq[i] = 0.f; }

    int srow[2], scol[2];
#pragma unroll
    for (int i = 0; i < 2; ++i) { const int cc = t + 256 * i; srow[i] = cc >> 3; scol[i] = (cc & 7) * 8; }

    for (int it = 0; it < 1024 / 64; ++it) {
        const int m0 = mc * 1024 + it * 64;

#pragma unroll
        for (int i = 0; i < 2; ++i) {
            *(bf16x8*)&adjT[srow[i] * 72 + scol[i]] =
                ld8(adj, (size_t)(m0 + srow[i]) * Nn + n0 + scol[i], F32);
            *(bf16x8*)&kT[srow[i] * 72 + scol[i]] =
                *(const bf16x8*)&g_kw[((size_t)(b * Nn + m0 + srow[i])) * 64 + scol[i]];
            *(bf16x8*)&vTl[srow[i] * 72 + scol[i]] =
                *(const bf16x8*)&g_vt[((size_t)(b * 64 + srow[i])) * Nn + m0 + scol[i]];
        }
        __syncthreads();

        // S = Q K^T (C layout: col=m=l16, row=n=quad*4+r), mask, sumsq
#pragma unroll
        for (int tm = 0; tm < 4; ++tm) {
            const ushort_t* kb = &kT[(tm * 16 + l16) * 72];
            bf16x8 k0 = *(const bf16x8*)(kb + quad * 8);
            bf16x8 k1 = *(const bf16x8*)(kb + 32 + quad * 8);
            floatx4 sv = mfma16(a1, k1, mfma16(a0, k0, z));
            ushort4v mv = *(const ushort4v*)&adjT[(tm * 16 + l16) * 72 + nnb];
#pragma unroll
            for (int r = 0; r < 4; ++r) {
                const float sm = sv[r] * bf2f(mv[r]);
                ssq[r] += sm * sm;
                sS[(nnb + r) * 72 + tm * 16 + l16] = f2bf(sm);
            }
        }
        __syncthreads();

        bf16x8 sa0 = *(const bf16x8*)&sS[(wv * 16 + l16) * 72 + quad * 8];
        bf16x8 sa1 = *(const bf16x8*)&sS[(wv * 16 + l16) * 72 + 32 + quad * 8];
#pragma unroll
        for (int td = 0; td < 4; ++td) {
            const ushort_t* vb = &vTl[(td * 16 + l16) * 72];
            bf16x8 v0 = *(const bf16x8*)(vb + quad * 8);
            bf16x8 v1 = *(const bf16x8*)(vb + 32 + quad * 8);
            acc[td] = mfma16(sa0, v0, acc[td]);
            acc[td] = mfma16(sa1, v1, acc[td]);
        }
        __syncthreads();
    }

    // partial ssq: reduce across the 16 l16 lanes of each row group
#pragma unroll
    for (int r = 0; r < 4; ++r) {
        float v = ssq[r];
        v += __shfl_xor(v, 1, 64);
        v += __shfl_xor(v, 2, 64);
        v += __shfl_xor(v, 4, 64);
        v += __shfl_xor(v, 8, 64);
        ssq[r] = v;
    }
    const size_t pbase = ((size_t)(b * 64 + nt) * MC + mc);
    if (l16 == 0) {
#pragma unroll
        for (int r = 0; r < 4; ++r)
            g_pss[pbase * 64 + nnb + r] = ssq[r];
    }
#pragma unroll
    for (int td = 0; td < 4; ++td)
#pragma unroll
        for (int r = 0; r < 4; ++r)
            g_pac[(pbase * 64 + nnb + r) * 64 + td * 16 + l16] = acc[td][r];
}

// ---------------------------------------------------------------------------
// Phase C: reduce partials + norm + Wu epilogue + output.
// grid B*(N/16)=1024 blocks x 256 thr; block = 16 rows, wave wv = col-tile wv.
// Partials are reduced straight into MFMA A-fragment registers.
// ---------------------------------------------------------------------------
__global__ __launch_bounds__(256) void finish_kernel(
    const void* __restrict__ hid, const void* __restrict__ adj,
    const void* __restrict__ Wui, const void* __restrict__ bui,
    const void* __restrict__ Wuo, const void* __restrict__ buo,
    const void* __restrict__ stepp, void* __restrict__ outp)
{
    const bool F32 = (*(const unsigned*)adj) == 0x3F800000u;

    const int bi = blockIdx.x;
    const int b = bi >> 8;
    const int r16 = bi & 255;
    const int n16 = r16 << 4;
    const int nt = r16 >> 2;
    const int nloc0 = (r16 & 3) << 4;  // row offset within the 64-tile
    const int t = threadIdx.x;
    const int wv = t >> 6, lane = t & 63, l16 = lane & 15, quad = lane >> 4;

    // reduce partial ssq over mc (lane's mc = quad), rows n16+l16
    const size_t sbase = ((size_t)(b * 64 + nt) * MC + quad) * 64 + nloc0 + l16;
    float sv = g_pss[sbase];
    sv += __shfl_xor(sv, 16, 64);
    sv += __shfl_xor(sv, 32, 64);
    const float inv = (sv > 0.f) ? __frsqrt_rn(sv) : 0.f;

    // reduce partial acc straight into A-frag layout: row=l16, k=quad*8+j
    float s0[8], s1[8];
#pragma unroll
    for (int j = 0; j < 8; ++j) { s0[j] = 0.f; s1[j] = 0.f; }
#pragma unroll
    for (int mcq = 0; mcq < MC; ++mcq) {
        const size_t abase =
            (((size_t)(b * 64 + nt) * MC + mcq) * 64 + nloc0 + l16) * 64 + quad * 8;
        float4 x0 = *(const float4*)&g_pac[abase];
        float4 x1 = *(const float4*)&g_pac[abase + 4];
        float4 y0 = *(const float4*)&g_pac[abase + 32];
        float4 y1 = *(const float4*)&g_pac[abase + 36];
        s0[0] += x0.x; s0[1] += x0.y; s0[2] += x0.z; s0[3] += x0.w;
        s0[4] += x1.x; s0[5] += x1.y; s0[6] += x1.z; s0[7] += x1.w;
        s1[0] += y0.x; s1[1] += y0.y; s1[2] += y0.z; s1[3] += y0.w;
        s1[4] += y1.x; s1[5] += y1.y; s1[6] += y1.z; s1[7] += y1.w;
    }
    bf16x8 ua0, ua1;
#pragma unroll
    for (int j = 0; j < 8; ++j) {
        ua0[j] = (__bf16)(s0[j] * inv);
        ua1[j] = (__bf16)(s1[j] * inv);
    }

    const bool inter = (n16 < T1c);
    const void* Wu = inter ? Wui : Wuo;
    const void* bu = inter ? bui : buo;
    const float step = ldS(stepp, 0, F32);

    // wave wv computes output col-tile ti = wv
    const int ti = wv;
    floatx4 z = {0.f, 0.f, 0.f, 0.f};
    const size_t wrow = (size_t)(ti * 16 + l16) * 64 + quad * 8;
    bf16x8 w0 = ld8(Wu, wrow, F32);
    bf16x8 w1 = ld8(Wu, wrow + 32, F32);
    floatx4 u = mfma16(ua1, w1, mfma16(ua0, w0, z));
    const float buv = ldS(bu, ti * 16 + l16, F32);
#pragma unroll
    for (int r = 0; r < 4; ++r) {
        const size_t idx = ((size_t)(b * Nn + n16 + quad * 4 + r)) * 64 + ti * 16 + l16;
        const float hv = ldS(hid, idx, F32);
        const float dtv = bf2f(g_dt[idx]);
        stOut(outp, idx, hv + step * dtv * (u[r] + buv), F32);
    }
}

extern "C" void kernel_launch(void* const* d_in, const int* in_sizes, int n_in,
                              void* d_out, int out_size, void* d_ws, size_t ws_size,
                              hipStream_t stream)
{
    const void* hid = d_in[0];
    // d_in[1] input_states: unused by the reference
    const void* adj = d_in[2];
    const void* Wq  = d_in[3];
    const void* Wk  = d_in[4];
    const void* Wv  = d_in[5];
    const void* Wui = d_in[6];
    const void* bui = d_in[7];
    const void* Wti = d_in[8];
    const void* bti = d_in[9];
    const void* Wuo = d_in[10];
    const void* buo = d_in[11];
    const void* Wto = d_in[12];
    const void* bto = d_in[13];
    const void* stepp = d_in[14];

    qkvt_kernel<<<dim3(Bb * (Nn / 16)), dim3(256), 0, stream>>>(
        hid, adj, Wq, Wk, Wv, Wti, bti, Wto, bto);
    attn_part_kernel<<<dim3(Bb * 64 * MC), dim3(256), 0, stream>>>(adj);
    finish_kernel<<<dim3(Bb * (Nn / 16)), dim3(256), 0, stream>>>(
        hid, adj, Wui, bui, Wuo, buo, stepp, d_out);
}

// Round 5
// 182.283 us; speedup vs baseline: 1.4061x; 1.0998x over previous
//
#include <hip/hip_runtime.h>
#include <hip/hip_bf16.h>
#include <math.h>

#define Bb 4
#define Nn 4096
#define Hh 64
#define T1c 3072
#define MC 4           // split-m chunks in attn_part

typedef unsigned short ushort_t;
typedef __bf16 bf16x8 __attribute__((ext_vector_type(8)));
typedef float floatx4 __attribute__((ext_vector_type(4)));
typedef float floatx16 __attribute__((ext_vector_type(16)));
typedef unsigned short ushort4v __attribute__((ext_vector_type(4)));

// Static device scratch, fully rewritten every call (no cross-call state).
__device__ ushort_t g_qw[(size_t)Bb * Nn * Hh];
__device__ ushort_t g_kw[(size_t)Bb * Nn * Hh];
__device__ ushort_t g_vt[(size_t)Bb * Nn * Hh];   // [B][H][N] transposed V
__device__ ushort_t g_dt[(size_t)Bb * Nn * Hh];
__device__ float    g_pac[(size_t)Bb * 64 * MC * 64 * 64]; // partial acc [b][nt][mc][n][d]
__device__ float    g_pss[(size_t)Bb * 64 * MC * 64];      // partial ssq [b][nt][mc][n]

__device__ __forceinline__ float bf2f(unsigned short u) {
    union { unsigned int i; float f; } c;
    c.i = ((unsigned int)u) << 16;
    return c.f;
}
__device__ __forceinline__ unsigned short f2bf(float f) {
    union { float f; unsigned int i; } c;
    c.f = f;
    unsigned int x = c.i;
    unsigned int r = (x + 0x7fffu + ((x >> 16) & 1u)) >> 16;  // RNE
    return (unsigned short)r;
}

// dtype-adaptive loaders (eidx = element index); F32 is the measured reality.
__device__ __forceinline__ bf16x8 ld8(const void* p, size_t eidx, bool f32) {
    if (f32) {
        const float* fp = (const float*)p + eidx;
        float4 x0 = *(const float4*)fp;
        float4 x1 = *(const float4*)(fp + 4);
        bf16x8 r;
        r[0] = (__bf16)x0.x; r[1] = (__bf16)x0.y; r[2] = (__bf16)x0.z; r[3] = (__bf16)x0.w;
        r[4] = (__bf16)x1.x; r[5] = (__bf16)x1.y; r[6] = (__bf16)x1.z; r[7] = (__bf16)x1.w;
        return r;
    }
    return *(const bf16x8*)((const ushort_t*)p + eidx);
}
__device__ __forceinline__ float ldS(const void* p, size_t eidx, bool f32) {
    return f32 ? ((const float*)p)[eidx] : bf2f(((const ushort_t*)p)[eidx]);
}
__device__ __forceinline__ void stOut(void* p, size_t eidx, float v, bool f32) {
    if (f32) ((float*)p)[eidx] = v;
    else ((ushort_t*)p)[eidx] = f2bf(v);
}

__device__ __forceinline__ floatx4 mfma16(bf16x8 a, bf16x8 b, floatx4 c) {
    return __builtin_amdgcn_mfma_f32_16x16x32_bf16(a, b, c, 0, 0, 0);
}
__device__ __forceinline__ floatx16 mfma32(bf16x8 a, bf16x8 b, floatx16 c) {
    return __builtin_amdgcn_mfma_f32_32x32x16_bf16(a, b, c, 0, 0, 0);
}

__device__ __forceinline__ float fast_tanh(float x) {
    float e = __expf(-2.0f * fabsf(x));
    float t = (1.0f - e) / (1.0f + e);
    return copysignf(t, x);
}

// ---------------------------------------------------------------------------
// Phase A: grid B*(N/16)=1024 blocks x 256 thr. Block = 16 rows; the 4 waves
// split by output: wv0->q, wv1->k, wv2->vT, wv3->dt.
// ---------------------------------------------------------------------------
__global__ __launch_bounds__(256) void qkvt_kernel(
    const void* __restrict__ hid, const void* __restrict__ adj,
    const void* __restrict__ Wq, const void* __restrict__ Wk,
    const void* __restrict__ Wv,
    const void* __restrict__ Wti, const void* __restrict__ bti,
    const void* __restrict__ Wto, const void* __restrict__ bto)
{
    const bool F32 = (*(const unsigned*)adj) == 0x3F800000u;

    const int bi = blockIdx.x;
    const int b = bi >> 8;
    const int n16 = (bi & 255) << 4;
    const int t = threadIdx.x;
    const int wv = t >> 6, lane = t & 63, l16 = lane & 15, quad = lane >> 4;
    const bool inter = (n16 < T1c);

    const void* W = (wv == 0) ? Wq : (wv == 1) ? Wk : (wv == 2) ? Wv
                    : (inter ? Wti : Wto);
    const void* bt = inter ? bti : bto;

    const size_t hbase = ((size_t)(b * Nn + n16 + l16)) * Hh + quad * 8;
    bf16x8 a0 = ld8(hid, hbase, F32);
    bf16x8 a1 = ld8(hid, hbase + 32, F32);
    floatx4 z = {0.f, 0.f, 0.f, 0.f};

    floatx4 c[4];
#pragma unroll
    for (int ti = 0; ti < 4; ++ti) {
        const size_t wrow = (size_t)(ti * 16 + l16) * 64 + quad * 8;
        bf16x8 w0 = ld8(W, wrow, F32);
        bf16x8 w1 = ld8(W, wrow + 32, F32);
        c[ti] = mfma16(a1, w1, mfma16(a0, w0, z));
    }

    if (wv == 0 || wv == 1) {
        ushort_t* dst = (wv == 0) ? g_qw : g_kw;
#pragma unroll
        for (int ti = 0; ti < 4; ++ti)
#pragma unroll
            for (int r = 0; r < 4; ++r)
                dst[((size_t)(b * Nn + n16 + quad * 4 + r)) * 64 + ti * 16 + l16] = f2bf(c[ti][r]);
    } else if (wv == 2) {
#pragma unroll
        for (int ti = 0; ti < 4; ++ti) {
            uint2 pk;
            pk.x = (unsigned)f2bf(c[ti][0]) | ((unsigned)f2bf(c[ti][1]) << 16);
            pk.y = (unsigned)f2bf(c[ti][2]) | ((unsigned)f2bf(c[ti][3]) << 16);
            *(uint2*)&g_vt[((size_t)(b * 64 + ti * 16 + l16)) * Nn + n16 + quad * 4] = pk;
        }
    } else {
#pragma unroll
        for (int ti = 0; ti < 4; ++ti) {
            const float btv = ldS(bt, ti * 16 + l16, F32);
#pragma unroll
            for (int r = 0; r < 4; ++r)
                g_dt[((size_t)(b * Nn + n16 + quad * 4 + r)) * 64 + ti * 16 + l16] =
                    f2bf(fast_tanh(0.5f * (c[ti][r] + btv)));
        }
    }
}

// ---------------------------------------------------------------------------
// Phase B: split-m attention partials, 32x32x16 MFMA + bitmask adjacency.
// grid B*64*MC = 1024 blocks x 256 thr. Wave wv -> quadrant (nh=wv>>1, mh=wv&1).
// Index swizzle: b-variants of a tile are 256 apart => same XCD (i%8) for L2 reuse.
// ---------------------------------------------------------------------------
__global__ __launch_bounds__(256, 4) void attn_part_kernel(
    const void* __restrict__ adj)
{
    const bool F32 = (*(const unsigned*)adj) == 0x3F800000u;

    __shared__ __align__(16) ushort_t kT[64 * 72];    // [m][h]
    __shared__ __align__(16) ushort_t vTl[64 * 72];   // [d][m]
    __shared__ __align__(16) ushort_t sS[64 * 72];    // masked S [n][m]
    __shared__ __align__(4)  unsigned char bmB[64 * 8]; // adjacency bits [m][n/8]
    __shared__ float ssqArr[4 * 64];

    const int bi = blockIdx.x;
    const int b  = bi >> 8;
    const int mc = bi & 3;
    const int nt = (bi >> 2) & 63;
    const int n0 = nt << 6;
    const int t = threadIdx.x;
    const int wv = t >> 6, lane = t & 63;
    const int l32 = lane & 31, h = lane >> 5;
    const int nh = wv >> 1, mh = wv & 1;

    // Q A-fragments: row = n0 + nh*32 + l32, k = h*8 + 16*i
    bf16x8 qf[4];
#pragma unroll
    for (int i = 0; i < 4; ++i)
        qf[i] = *(const bf16x8*)&g_qw[((size_t)(b * Nn + n0 + nh * 32 + l32)) * 64 + h * 8 + 16 * i];

    floatx16 acc;
    float ssq[16];
#pragma unroll
    for (int r = 0; r < 16; ++r) { acc[r] = 0.f; ssq[r] = 0.f; }

    int srow[2], scol[2];
#pragma unroll
    for (int i = 0; i < 2; ++i) { const int cc = t + 256 * i; srow[i] = cc >> 3; scol[i] = (cc & 7) * 8; }

    for (int it = 0; it < 1024 / 64; ++it) {
        const int m0 = mc * 1024 + it * 64;

        // stage K-tile, V^T-tile, adjacency bitmask
#pragma unroll
        for (int i = 0; i < 2; ++i) {
            *(bf16x8*)&kT[srow[i] * 72 + scol[i]] =
                *(const bf16x8*)&g_kw[((size_t)(b * Nn + m0 + srow[i])) * 64 + scol[i]];
            *(bf16x8*)&vTl[srow[i] * 72 + scol[i]] =
                *(const bf16x8*)&g_vt[((size_t)(b * 64 + srow[i])) * Nn + m0 + scol[i]];
            unsigned byte = 0;
            if (F32) {
                const float* fp = (const float*)adj + (size_t)(m0 + srow[i]) * Nn + n0 + scol[i];
                float4 x0 = *(const float4*)fp;
                float4 x1 = *(const float4*)(fp + 4);
                byte = (unsigned)(x0.x != 0.f)        | ((unsigned)(x0.y != 0.f) << 1)
                     | ((unsigned)(x0.z != 0.f) << 2) | ((unsigned)(x0.w != 0.f) << 3)
                     | ((unsigned)(x1.x != 0.f) << 4) | ((unsigned)(x1.y != 0.f) << 5)
                     | ((unsigned)(x1.z != 0.f) << 6) | ((unsigned)(x1.w != 0.f) << 7);
            } else {
                const ushort_t* up = (const ushort_t*)adj + (size_t)(m0 + srow[i]) * Nn + n0 + scol[i];
#pragma unroll
                for (int j = 0; j < 8; ++j) byte |= (unsigned)(up[j] != 0) << j;
            }
            bmB[srow[i] * 8 + (scol[i] >> 3)] = (unsigned char)byte;
        }
        __syncthreads();

        // S quadrant = Q K^T (32x32, C: col=m=l32, row=n=rowpat)
        floatx16 s;
#pragma unroll
        for (int r = 0; r < 16; ++r) s[r] = 0.f;
#pragma unroll
        for (int i = 0; i < 4; ++i) {
            bf16x8 kf = *(const bf16x8*)&kT[(mh * 32 + l32) * 72 + h * 8 + 16 * i];
            s = mfma32(qf[i], kf, s);
        }
        const unsigned mw = *(const unsigned*)&bmB[(mh * 32 + l32) * 8 + nh * 4];
        __bf16* sSb = (__bf16*)sS;
#pragma unroll
        for (int r = 0; r < 16; ++r) {
            const int rp = (r & 3) + 8 * (r >> 2) + 4 * h;   // row-within-32 / bit index
            const float sm = ((mw >> rp) & 1u) ? s[r] : 0.f;
            ssq[r] += sm * sm;
            sSb[(nh * 32 + rp) * 72 + mh * 32 + l32] = (__bf16)sm;
        }
        __syncthreads();

        // PV: acc quadrant (nh rows, dh=mh cols), A = S, B = V^T
#pragma unroll
        for (int i = 0; i < 4; ++i) {
            bf16x8 sf = *(const bf16x8*)&sS[(nh * 32 + l32) * 72 + h * 8 + 16 * i];
            bf16x8 vf = *(const bf16x8*)&vTl[(mh * 32 + l32) * 72 + h * 8 + 16 * i];
            acc = mfma32(sf, vf, acc);
        }
        __syncthreads();
    }

    const size_t pbase = ((size_t)(b * 64 + nt) * MC + mc);

    // ssq: sum across the 32 m-lanes of each half
#pragma unroll
    for (int r = 0; r < 16; ++r) {
        float v = ssq[r];
        v += __shfl_xor(v, 1, 64);
        v += __shfl_xor(v, 2, 64);
        v += __shfl_xor(v, 4, 64);
        v += __shfl_xor(v, 8, 64);
        v += __shfl_xor(v, 16, 64);
        ssq[r] = v;
    }
    if (l32 == 0) {
#pragma unroll
        for (int r = 0; r < 16; ++r) {
            const int rp = (r & 3) + 8 * (r >> 2) + 4 * h;
            ssqArr[wv * 64 + nh * 32 + rp] = ssq[r];
        }
    }
    __syncthreads();
    if (t < 64) {
        const int w0 = (t >> 5) * 2;  // rows 0-31 from waves 0,1; rows 32-63 from 2,3
        g_pss[pbase * 64 + t] = ssqArr[w0 * 64 + t] + ssqArr[(w0 + 1) * 64 + t];
    }

    // partial acc: C layout, lanes 0-31 write 128B contiguous per reg
#pragma unroll
    for (int r = 0; r < 16; ++r) {
        const int n = nh * 32 + (r & 3) + 8 * (r >> 2) + 4 * h;
        g_pac[(pbase * 64 + n) * 64 + mh * 32 + l32] = acc[r];
    }
}

// ---------------------------------------------------------------------------
// Phase C: reduce partials + norm + Wu epilogue + output.
// ---------------------------------------------------------------------------
__global__ __launch_bounds__(256) void finish_kernel(
    const void* __restrict__ hid, const void* __restrict__ adj,
    const void* __restrict__ Wui, const void* __restrict__ bui,
    const void* __restrict__ Wuo, const void* __restrict__ buo,
    const void* __restrict__ stepp, void* __restrict__ outp)
{
    const bool F32 = (*(const unsigned*)adj) == 0x3F800000u;

    const int bi = blockIdx.x;
    const int b = bi >> 8;
    const int r16 = bi & 255;
    const int n16 = r16 << 4;
    const int nt = r16 >> 2;
    const int nloc0 = (r16 & 3) << 4;
    const int t = threadIdx.x;
    const int wv = t >> 6, lane = t & 63, l16 = lane & 15, quad = lane >> 4;

    const size_t sbase = ((size_t)(b * 64 + nt) * MC + quad) * 64 + nloc0 + l16;
    float sv = g_pss[sbase];
    sv += __shfl_xor(sv, 16, 64);
    sv += __shfl_xor(sv, 32, 64);
    const float inv = (sv > 0.f) ? __frsqrt_rn(sv) : 0.f;

    float s0[8], s1[8];
#pragma unroll
    for (int j = 0; j < 8; ++j) { s0[j] = 0.f; s1[j] = 0.f; }
#pragma unroll
    for (int mcq = 0; mcq < MC; ++mcq) {
        const size_t abase =
            (((size_t)(b * 64 + nt) * MC + mcq) * 64 + nloc0 + l16) * 64 + quad * 8;
        float4 x0 = *(const float4*)&g_pac[abase];
        float4 x1 = *(const float4*)&g_pac[abase + 4];
        float4 y0 = *(const float4*)&g_pac[abase + 32];
        float4 y1 = *(const float4*)&g_pac[abase + 36];
        s0[0] += x0.x; s0[1] += x0.y; s0[2] += x0.z; s0[3] += x0.w;
        s0[4] += x1.x; s0[5] += x1.y; s0[6] += x1.z; s0[7] += x1.w;
        s1[0] += y0.x; s1[1] += y0.y; s1[2] += y0.z; s1[3] += y0.w;
        s1[4] += y1.x; s1[5] += y1.y; s1[6] += y1.z; s1[7] += y1.w;
    }
    bf16x8 ua0, ua1;
#pragma unroll
    for (int j = 0; j < 8; ++j) {
        ua0[j] = (__bf16)(s0[j] * inv);
        ua1[j] = (__bf16)(s1[j] * inv);
    }

    const bool inter = (n16 < T1c);
    const void* Wu = inter ? Wui : Wuo;
    const void* bu = inter ? bui : buo;
    const float step = ldS(stepp, 0, F32);

    const int ti = wv;
    floatx4 z = {0.f, 0.f, 0.f, 0.f};
    const size_t wrow = (size_t)(ti * 16 + l16) * 64 + quad * 8;
    bf16x8 w0 = ld8(Wu, wrow, F32);
    bf16x8 w1 = ld8(Wu, wrow + 32, F32);
    floatx4 u = mfma16(ua1, w1, mfma16(ua0, w0, z));
    const float buv = ldS(bu, ti * 16 + l16, F32);
#pragma unroll
    for (int r = 0; r < 4; ++r) {
        const size_t idx = ((size_t)(b * Nn + n16 + quad * 4 + r)) * 64 + ti * 16 + l16;
        const float hv = ldS(hid, idx, F32);
        const float dtv = bf2f(g_dt[idx]);
        stOut(outp, idx, hv + step * dtv * (u[r] + buv), F32);
    }
}

extern "C" void kernel_launch(void* const* d_in, const int* in_sizes, int n_in,
                              void* d_out, int out_size, void* d_ws, size_t ws_size,
                              hipStream_t stream)
{
    const void* hid = d_in[0];
    const void* adj = d_in[2];
    const void* Wq  = d_in[3];
    const void* Wk  = d_in[4];
    const void* Wv  = d_in[5];
    const void* Wui = d_in[6];
    const void* bui = d_in[7];
    const void* Wti = d_in[8];
    const void* bti = d_in[9];
    const void* Wuo = d_in[10];
    const void* buo = d_in[11];
    const void* Wto = d_in[12];
    const void* bto = d_in[13];
    const void* stepp = d_in[14];

    qkvt_kernel<<<dim3(Bb * (Nn / 16)), dim3(256), 0, stream>>>(
        hid, adj, Wq, Wk, Wv, Wti, bti, Wto, bto);
    attn_part_kernel<<<dim3(Bb * 64 * MC), dim3(256), 0, stream>>>(adj);
    finish_kernel<<<dim3(Bb * (Nn / 16)), dim3(256), 0, stream>>>(
        hid, adj, Wui, bui, Wuo, buo, stepp, d_out);
}